// Round 4
// baseline (505.351 us; speedup 1.0000x reference)
//
#include <hip/hip_runtime.h>

typedef __bf16 bf16x8 __attribute__((ext_vector_type(8)));
typedef float f32x4 __attribute__((ext_vector_type(4)));
typedef int i32x4 __attribute__((ext_vector_type(4)));

#define DEV __device__ __forceinline__
#define AS1 __attribute__((address_space(1)))
#define AS3 __attribute__((address_space(3)))

DEV unsigned short f2bf(float f) {
  union { float f; unsigned u; } x; x.f = f;
  unsigned r = x.u + 0x7fffu + ((x.u >> 16) & 1u);
  return (unsigned short)(r >> 16);
}

DEV unsigned pkbf(float a, float b) {  // packs {lo=a, hi=b} as 2x bf16 (RNE)
  unsigned r;
  asm("v_cvt_pk_bf16_f32 %0, %1, %2" : "=v"(r) : "v"(a), "v"(b));
  return r;
}

DEV f32x4 mfma16(bf16x8 a, bf16x8 b, f32x4 c) {
  return __builtin_amdgcn_mfma_f32_16x16x32_bf16(a, b, c, 0, 0, 0);
}

#if __has_builtin(__builtin_amdgcn_exp2f)
DEV float xexp2(float x) { return __builtin_amdgcn_exp2f(x); }
#else
DEV float xexp2(float x) { return __expf(x * 0.6931471805599453f); }
#endif

DEV void gload16(const void* g, void* lds) {
  __builtin_amdgcn_global_load_lds((const AS1 void*)g, (AS3 void*)lds, 16, 0, 0);
}

// ---------------- fp32 -> bf16 conversion ----------------
__global__ void f2b_kernel(const float* __restrict__ src, unsigned short* __restrict__ dst, int n) {
  int i = (blockIdx.x * blockDim.x + threadIdx.x) * 4;
  int stride = gridDim.x * blockDim.x * 4;
  for (; i < n; i += stride) {
    float4 v = *reinterpret_cast<const float4*>(src + i);
    ushort4 o;
    o.x = f2bf(v.x); o.y = f2bf(v.y); o.z = f2bf(v.z); o.w = f2bf(v.w);
    *reinterpret_cast<ushort4*>(dst + i) = o;
  }
}

// ---------------- GEMM (m97 structure): C[M,N] = A[M,K] * B[N,K]^T + bias ----------------
template <int EPI>
__global__ __launch_bounds__(256, 2)
void gemm_bt(const unsigned short* __restrict__ A, const unsigned short* __restrict__ B,
             const float* __restrict__ bias, void* __restrict__ outv,
             int M, int N, int K) {
  __shared__ __align__(16) unsigned short As[128 * 64];
  __shared__ __align__(16) unsigned short Bs[128 * 64];
  const int tid = threadIdx.x;
  const int l = tid & 63, w = tid >> 6;
  const int wr = w >> 1, wc = w & 1;
  const int tm = blockIdx.x * 128, tn = blockIdx.y * 128;
  const int lr = l >> 3, lc = (l & 7) * 8;

  f32x4 acc[4][4] = {};

  for (int kt = 0; kt < K; kt += 64) {
#pragma unroll
    for (int i = 0; i < 4; ++i) {
      int c = i * 4 + w;
      gload16(A + (size_t)(tm + c * 8 + lr) * K + kt + lc, (char*)As + c * 1024);
    }
#pragma unroll
    for (int i = 0; i < 4; ++i) {
      int c = i * 4 + w;
      gload16(B + (size_t)(tn + c * 8 + lr) * K + kt + lc, (char*)Bs + c * 1024);
    }
    __syncthreads();
#pragma unroll
    for (int ks = 0; ks < 2; ++ks) {
      int ko = ks * 32 + (l >> 4) * 8;
      bf16x8 af[4], bfr[4];
#pragma unroll
      for (int i = 0; i < 4; ++i) {
        af[i]  = *reinterpret_cast<const bf16x8*>(As + (wr * 64 + i * 16 + (l & 15)) * 64 + ko);
        bfr[i] = *reinterpret_cast<const bf16x8*>(Bs + (wc * 64 + i * 16 + (l & 15)) * 64 + ko);
      }
#pragma unroll
      for (int mi = 0; mi < 4; ++mi)
#pragma unroll
        for (int ni = 0; ni < 4; ++ni)
          acc[mi][ni] = mfma16(af[mi], bfr[ni], acc[mi][ni]);
    }
    __syncthreads();
  }

#pragma unroll
  for (int ni = 0; ni < 4; ++ni) {
    int n = tn + wc * 64 + ni * 16 + (l & 15);
    float bv = bias[n];
    if (EPI == 0) {
      float* out = (float*)outv;
#pragma unroll
      for (int mi = 0; mi < 4; ++mi)
#pragma unroll
        for (int r = 0; r < 4; ++r) {
          int m = tm + wr * 64 + mi * 16 + (l >> 4) * 4 + r;
          out[(size_t)m * N + n] = acc[mi][ni][r] + bv;
        }
    } else {
      unsigned short* out = (unsigned short*)outv;
      int s = n >> 10, rem = n & 1023, h = rem >> 6, d = rem & 63;
#pragma unroll
      for (int mi = 0; mi < 4; ++mi)
#pragma unroll
        for (int r = 0; r < 4; ++r) {
          int m = tm + wr * 64 + mi * 16 + (l >> 4) * 4 + r;
          int b = m >> 11, t = m & 2047;
          size_t off = ((((size_t)s * 4 + b) * 16 + h) * 2048 + t) * 64 + d;
          out[off] = f2bf(acc[mi][ni][r] + bv);
        }
    }
  }
}

// ---------------- Attention (swapped-S, swizzled LDS, 2-phase prefetch) ----------------
// grid (bh=64, 16), qt = 15 - by (LPT). block 256 = 4 waves x 32 q-rows.
// S^T = mfma(A=K, B=Q): lane holds S[k = kA*16+g*4+r][q = qB*16+i] -> k-contiguous f32x4.
// O^T = mfma(A=V^T, B=P): P round-trips LDS as b64 writes / b128 reads, wave-private.
__global__ __launch_bounds__(256, 2)
void attn_kernel(const unsigned short* __restrict__ qkv, float* __restrict__ attnW,
                 unsigned short* __restrict__ Ob) {
  __shared__ __align__(16) unsigned short Qs[128 * 64];
  __shared__ __align__(16) unsigned short Ks[2][64 * 64];
  __shared__ __align__(16) unsigned short VsT[2][64 * 64];
  __shared__ __align__(16) unsigned short Ps[4][32 * 64];

  const int tid = threadIdx.x, l = tid & 63, w = tid >> 6;
  const int li = l & 15, g = l >> 4;
  const int bh = blockIdx.x;
  const int qt = 15 - (int)blockIdx.y;
  const int b = bh >> 4, hh = bh & 15;
  const size_t plane = (size_t)2048 * 64;
  const unsigned short* Qg = qkv + ((size_t)0 * 64 + bh) * plane;
  const unsigned short* Kg = qkv + ((size_t)1 * 64 + bh) * plane;
  const unsigned short* Vg = qkv + ((size_t)2 * 64 + bh) * plane;
  const int q0 = qt * 128;
  const int nkt = 2 * qt + 2;
  const float cexp = 0.1803368801f;  // 0.125 * log2(e)

  // ---- stage Q (once), XOR-swizzled rows of 128B ----
#pragma unroll
  for (int it = 0; it < 4; ++it) {
    int c = it * 256 + tid;
    int row = c >> 3, ch = c & 7;
    *reinterpret_cast<i32x4*>(Qs + row * 64 + ((ch ^ (row & 7)) * 8)) =
        *reinterpret_cast<const i32x4*>(Qg + (size_t)(q0 + row) * 64 + ch * 8);
  }

  auto stageK = [&](int kt, int buf) {
#pragma unroll
    for (int it = 0; it < 2; ++it) {
      int c = it * 4 + w;
      int X = c * 1024 + l * 16;          // dest byte for this lane
      int row = X >> 7, sl = (X >> 4) & 7;
      gload16(Kg + (size_t)(kt * 64 + row) * 64 + ((sl ^ (row & 7)) * 8),
              (char*)Ks[buf] + c * 1024);
    }
  };

  auto computeS = [&](int buf, f32x4 s[4][2]) {
#pragma unroll
    for (int ks = 0; ks < 2; ++ks) {
      bf16x8 ak[4], bq[2];
      int cc = ks * 4 + g;
#pragma unroll
      for (int kA = 0; kA < 4; ++kA) {
        int kr = kA * 16 + li;
        ak[kA] = *reinterpret_cast<const bf16x8*>(Ks[buf] + kr * 64 + ((cc ^ (kr & 7)) * 8));
      }
#pragma unroll
      for (int qB = 0; qB < 2; ++qB) {
        int qr = w * 32 + qB * 16 + li;
        bq[qB] = *reinterpret_cast<const bf16x8*>(Qs + qr * 64 + ((cc ^ (qr & 7)) * 8));
      }
#pragma unroll
      for (int kA = 0; kA < 4; ++kA)
#pragma unroll
        for (int qB = 0; qB < 2; ++qB)
          s[kA][qB] = mfma16(ak[kA], bq[qB], s[kA][qB]);
    }
  };

  // ---- pass 1: row denominators (m = 0) ----
  float lsum[2] = {0.f, 0.f};
  stageK(0, 0);
  for (int kt = 0; kt < nkt; ++kt) {
    __syncthreads();                       // drains stageK(kt)
    if (kt + 1 < nkt) stageK(kt + 1, (kt + 1) & 1);
    f32x4 s[4][2] = {};
    computeS(kt & 1, s);
    const bool dg = (kt >= 2 * qt);
#pragma unroll
    for (int qB = 0; qB < 2; ++qB) {
      int qg = q0 + w * 32 + qB * 16 + li;
      float a = 0.f;
#pragma unroll
      for (int kA = 0; kA < 4; ++kA)
#pragma unroll
        for (int r = 0; r < 4; ++r) {
          float e = xexp2(s[kA][qB][r] * cexp);
          if (dg) { int k = kt * 64 + kA * 16 + g * 4 + r; e = (k <= qg) ? e : 0.f; }
          a += e;
        }
      lsum[qB] += a;
    }
  }

  float linv[2];
#pragma unroll
  for (int qB = 0; qB < 2; ++qB) {
    float v = lsum[qB];
    v += __shfl_xor(v, 16, 64);
    v += __shfl_xor(v, 32, 64);
    linv[qB] = 1.0f / v;
  }

  // ---- pass 2: P stores + O = P@V ----
  __syncthreads();  // all pass-1 reads of Ks done before restaging buf 0
  i32x4 vr0, vr1;
  stageK(0, 0);
  vr0 = *reinterpret_cast<const i32x4*>(Vg + (size_t)l * 64 + w * 16);
  vr1 = *reinterpret_cast<const i32x4*>(Vg + (size_t)l * 64 + w * 16 + 8);
  {
    union { i32x4 v; unsigned short u[8]; } ua, ub;
    ua.v = vr0; ub.v = vr1;
#pragma unroll
    for (int j = 0; j < 8; ++j) {
      int ce = ((l >> 3) ^ j) * 8 + (l & 7);
      VsT[0][(w * 16 + j) * 64 + ce] = ua.u[j];
      VsT[0][(w * 16 + 8 + j) * 64 + ce] = ub.u[j];
    }
  }

  f32x4 o[2][4] = {};
  int cb = 0;
  unsigned short* PsW = &Ps[w][0];

  for (int kt = 0; kt < nkt; ++kt) {
    __syncthreads();                       // stageK(kt) drained, VsT(kt) visible
    const int nb = cb ^ 1;
    i32x4 nv0, nv1;
    if (kt + 1 < nkt) {
      stageK(kt + 1, nb);
      nv0 = *reinterpret_cast<const i32x4*>(Vg + (size_t)((kt + 1) * 64 + l) * 64 + w * 16);
      nv1 = *reinterpret_cast<const i32x4*>(Vg + (size_t)((kt + 1) * 64 + l) * 64 + w * 16 + 8);
    }

    f32x4 s[4][2] = {};
    computeS(cb, s);

    const bool dg = (kt >= 2 * qt);
#pragma unroll
    for (int kA = 0; kA < 4; ++kA)
#pragma unroll
      for (int qB = 0; qB < 2; ++qB) {
        int qg = q0 + w * 32 + qB * 16 + li;
        f32x4 e;
#pragma unroll
        for (int r = 0; r < 4; ++r) {
          float v = xexp2(s[kA][qB][r] * cexp) * linv[qB];
          if (dg) { int k = kt * 64 + kA * 16 + g * 4 + r; v = (k <= qg) ? v : 0.f; }
          e[r] = v;
        }
        // direct fp32 store of 4 consecutive k
        *reinterpret_cast<f32x4*>(attnW + ((size_t)bh * 2048 + qg) * 2048 + kt * 64 + kA * 16 + g * 4) = e;
        // pack to bf16 pairs, b64 LDS write (wave-private)
        uint2 pk;
        pk.x = pkbf(e[0], e[1]);
        pk.y = pkbf(e[2], e[3]);
        int qr = qB * 16 + li;
        *reinterpret_cast<uint2*>((char*)PsW + qr * 128 + ((kA * 32 + g * 8) ^ ((qr & 7) << 4))) = pk;
      }

    __builtin_amdgcn_wave_barrier();  // keep Ps writes before reads in schedule

    // O^T += V^T x P  (A = V^T frag, B = P frag)
#pragma unroll
    for (int ks = 0; ks < 2; ++ks) {
      int cc = ks * 4 + g;
      bf16x8 av[4], bp[2];
#pragma unroll
      for (int df = 0; df < 4; ++df) {
        int dr = df * 16 + li;
        av[df] = *reinterpret_cast<const bf16x8*>(VsT[cb] + dr * 64 + ((cc ^ (dr & 7)) * 8));
      }
#pragma unroll
      for (int qB = 0; qB < 2; ++qB) {
        int qr = qB * 16 + li;
        bp[qB] = *reinterpret_cast<const bf16x8*>((const char*)PsW + qr * 128 + ((ks * 64 + g * 16) ^ ((qr & 7) << 4)));
      }
#pragma unroll
      for (int qB = 0; qB < 2; ++qB)
#pragma unroll
        for (int df = 0; df < 4; ++df)
          o[qB][df] = mfma16(av[df], bp[qB], o[qB][df]);
    }

    if (kt + 1 < nkt) {
      union { i32x4 v; unsigned short u[8]; } ua, ub;
      ua.v = nv0; ub.v = nv1;
#pragma unroll
      for (int j = 0; j < 8; ++j) {
        int ce = ((l >> 3) ^ j) * 8 + (l & 7);
        VsT[nb][(w * 16 + j) * 64 + ce] = ua.u[j];
        VsT[nb][(w * 16 + 8 + j) * 64 + ce] = ub.u[j];
      }
    }
    cb = nb;
  }

  // ---- O store: lane holds q = qB*16+li, d = df*16 + g*4 + r ----
#pragma unroll
  for (int qB = 0; qB < 2; ++qB) {
    int qg = q0 + w * 32 + qB * 16 + li;
#pragma unroll
    for (int df = 0; df < 4; ++df) {
      ushort4 ov;
      ov.x = f2bf(o[qB][df][0]);
      ov.y = f2bf(o[qB][df][1]);
      ov.z = f2bf(o[qB][df][2]);
      ov.w = f2bf(o[qB][df][3]);
      *reinterpret_cast<ushort4*>(Ob + ((size_t)b * 2048 + qg) * 1024 + hh * 64 + df * 16 + g * 4) = ov;
    }
  }

  // ---- zero-fill masked-out columns (cols >= 128*(qt+1)) ----
  {
    int col0 = 128 * (qt + 1);
    int nch = (2048 - col0) >> 2;
    float4 z = make_float4(0.f, 0.f, 0.f, 0.f);
    for (int row = 0; row < 128; ++row) {
      size_t base = ((size_t)bh * 2048 + (q0 + row)) * 2048 + col0;
      for (int c = tid; c < nch; c += 256)
        *reinterpret_cast<float4*>(attnW + base + (size_t)c * 4) = z;
    }
  }
}

extern "C" void kernel_launch(void* const* d_in, const int* in_sizes, int n_in,
                              void* d_out, int out_size, void* d_ws, size_t ws_size,
                              hipStream_t stream) {
  const float* x  = (const float*)d_in[0];
  const float* w1 = (const float*)d_in[1];
  const float* b1 = (const float*)d_in[2];
  const float* w2 = (const float*)d_in[3];
  const float* b2 = (const float*)d_in[4];
  float* out = (float*)d_out;
  float* attnW = out + (size_t)8192 * 1024;

  unsigned short* xb   = (unsigned short*)d_ws;
  unsigned short* w1b  = xb + (size_t)8192 * 1024;
  unsigned short* w2b  = w1b + (size_t)3072 * 1024;
  unsigned short* qkvb = w2b + (size_t)1024 * 1024;
  unsigned short* ob   = qkvb + (size_t)3 * 8192 * 1024;

  f2b_kernel<<<1024, 256, 0, stream>>>(x, xb, 8192 * 1024);
  f2b_kernel<<<512, 256, 0, stream>>>(w1, w1b, 3072 * 1024);
  f2b_kernel<<<256, 256, 0, stream>>>(w2, w2b, 1024 * 1024);

  gemm_bt<1><<<dim3(64, 24), 256, 0, stream>>>(xb, w1b, b1, qkvb, 8192, 3072, 1024);

  attn_kernel<<<dim3(64, 16), 256, 0, stream>>>(qkvb, attnW, ob);

  gemm_bt<0><<<dim3(64, 8), 256, 0, stream>>>(ob, w2b, b2, out, 8192, 1024, 1024);
}

// Round 6
// 469.938 us; speedup vs baseline: 1.0754x; 1.0754x over previous
//
#include <hip/hip_runtime.h>

typedef __bf16 bf16x8 __attribute__((ext_vector_type(8)));
typedef float f32x4 __attribute__((ext_vector_type(4)));
typedef int i32x4 __attribute__((ext_vector_type(4)));

#define DEV __device__ __forceinline__
#define AS1 __attribute__((address_space(1)))
#define AS3 __attribute__((address_space(3)))

DEV unsigned short f2bf(float f) {
  union { float f; unsigned u; } x; x.f = f;
  unsigned r = x.u + 0x7fffu + ((x.u >> 16) & 1u);
  return (unsigned short)(r >> 16);
}

DEV unsigned pkbf(float a, float b) {  // packs {lo=a, hi=b} as 2x bf16 (RNE)
  unsigned r;
  asm("v_cvt_pk_bf16_f32 %0, %1, %2" : "=v"(r) : "v"(a), "v"(b));
  return r;
}

DEV f32x4 mfma16(bf16x8 a, bf16x8 b, f32x4 c) {
  return __builtin_amdgcn_mfma_f32_16x16x32_bf16(a, b, c, 0, 0, 0);
}

#if __has_builtin(__builtin_amdgcn_exp2f)
DEV float xexp2(float x) { return __builtin_amdgcn_exp2f(x); }
#else
DEV float xexp2(float x) { return __expf(x * 0.6931471805599453f); }
#endif

DEV void gload16(const void* g, void* lds) {
  __builtin_amdgcn_global_load_lds((const AS1 void*)g, (AS3 void*)lds, 16, 0, 0);
}

// ---------------- fp32 -> bf16 conversion ----------------
__global__ void f2b_kernel(const float* __restrict__ src, unsigned short* __restrict__ dst, int n) {
  int i = (blockIdx.x * blockDim.x + threadIdx.x) * 4;
  int stride = gridDim.x * blockDim.x * 4;
  for (; i < n; i += stride) {
    float4 v = *reinterpret_cast<const float4*>(src + i);
    ushort4 o;
    o.x = f2bf(v.x); o.y = f2bf(v.y); o.z = f2bf(v.z); o.w = f2bf(v.w);
    *reinterpret_cast<ushort4*>(dst + i) = o;
  }
}

// ---------------- GEMM (m97 structure): C[M,N] = A[M,K] * B[N,K]^T + bias ----------------
// EPI 0: fp32 row-major [M][N].
// EPI 1: qkv scatter. Q (s=0): [bh][t][64] bf16, PRE-SCALED by 0.125*log2(e).
//        K (s=1): [64+bh][t][64].  V (s=2): TRANSPOSED [128+bh][64 d][2048 t].
template <int EPI>
__global__ __launch_bounds__(256, 2)
void gemm_bt(const unsigned short* __restrict__ A, const unsigned short* __restrict__ B,
             const float* __restrict__ bias, void* __restrict__ outv,
             int M, int N, int K) {
  __shared__ __align__(16) unsigned short As[128 * 64];
  __shared__ __align__(16) unsigned short Bs[128 * 64];
  const int tid = threadIdx.x;
  const int l = tid & 63, w = tid >> 6;
  const int wr = w >> 1, wc = w & 1;
  const int tm = blockIdx.x * 128, tn = blockIdx.y * 128;
  const int lr = l >> 3, lc = (l & 7) * 8;

  f32x4 acc[4][4] = {};

  for (int kt = 0; kt < K; kt += 64) {
#pragma unroll
    for (int i = 0; i < 4; ++i) {
      int c = i * 4 + w;
      gload16(A + (size_t)(tm + c * 8 + lr) * K + kt + lc, (char*)As + c * 1024);
    }
#pragma unroll
    for (int i = 0; i < 4; ++i) {
      int c = i * 4 + w;
      gload16(B + (size_t)(tn + c * 8 + lr) * K + kt + lc, (char*)Bs + c * 1024);
    }
    __syncthreads();
#pragma unroll
    for (int ks = 0; ks < 2; ++ks) {
      int ko = ks * 32 + (l >> 4) * 8;
      bf16x8 af[4], bfr[4];
#pragma unroll
      for (int i = 0; i < 4; ++i) {
        af[i]  = *reinterpret_cast<const bf16x8*>(As + (wr * 64 + i * 16 + (l & 15)) * 64 + ko);
        bfr[i] = *reinterpret_cast<const bf16x8*>(Bs + (wc * 64 + i * 16 + (l & 15)) * 64 + ko);
      }
#pragma unroll
      for (int mi = 0; mi < 4; ++mi)
#pragma unroll
        for (int ni = 0; ni < 4; ++ni)
          acc[mi][ni] = mfma16(af[mi], bfr[ni], acc[mi][ni]);
    }
    __syncthreads();
  }

#pragma unroll
  for (int ni = 0; ni < 4; ++ni) {
    int n = tn + wc * 64 + ni * 16 + (l & 15);
    float bv = bias[n];
    if (EPI == 0) {
      float* out = (float*)outv;
#pragma unroll
      for (int mi = 0; mi < 4; ++mi)
#pragma unroll
        for (int r = 0; r < 4; ++r) {
          int m = tm + wr * 64 + mi * 16 + (l >> 4) * 4 + r;
          out[(size_t)m * N + n] = acc[mi][ni][r] + bv;
        }
    } else {
      unsigned short* out = (unsigned short*)outv;
      int s = n >> 10, rem = n & 1023, h = rem >> 6, d = rem & 63;
      if (s == 2) {
        // V transposed: [128 + bh][d][t], 4 consecutive t per lane -> ushort4
#pragma unroll
        for (int mi = 0; mi < 4; ++mi) {
          int m = tm + wr * 64 + mi * 16 + (l >> 4) * 4;
          int bb = m >> 11, t = m & 2047;
          ushort4 pv;
          pv.x = f2bf(acc[mi][ni][0] + bv);
          pv.y = f2bf(acc[mi][ni][1] + bv);
          pv.z = f2bf(acc[mi][ni][2] + bv);
          pv.w = f2bf(acc[mi][ni][3] + bv);
          size_t off = ((size_t)(128 + bb * 16 + h)) * 131072 + (size_t)d * 2048 + t;
          *reinterpret_cast<ushort4*>(out + off) = pv;
        }
      } else {
        const float sc = (s == 0) ? 0.1803368801f : 1.0f;  // fold 0.125*log2(e) into Q
#pragma unroll
        for (int mi = 0; mi < 4; ++mi)
#pragma unroll
          for (int r = 0; r < 4; ++r) {
            int m = tm + wr * 64 + mi * 16 + (l >> 4) * 4 + r;
            int bb = m >> 11, t = m & 2047;
            size_t off = ((((size_t)s * 4 + bb) * 16 + h) * 2048 + t) * 64 + d;
            out[off] = f2bf((acc[mi][ni][r] + bv) * sc);
          }
      }
    }
  }
}

// ---------------- Attention ----------------
// 1024 blocks 1-D, XCD-chunked: xcd = id&7 gets 8 heads x all 16 qt (LPT: qt desc).
// 4 waves x 32 q-rows. Q in registers (pre-scaled). K, V^T staged via gload_lds
// (XOR-swizzled source). Pass 2 uses raw s_barrier + counted vmcnt(8) so the 8
// attnW stores of tile kt ride through tile kt+1's compute (T4).
__global__ __launch_bounds__(256, 3)
void attn_kernel(const unsigned short* __restrict__ qkv, float* __restrict__ attnW,
                 unsigned short* __restrict__ Ob) {
  __shared__ __align__(16) unsigned short Ks[2][64 * 64];
  __shared__ __align__(16) unsigned short VsT[2][64 * 64];
  __shared__ __align__(16) unsigned short Ps[4][32 * 64];

  const int tid = threadIdx.x, l = tid & 63, w = tid >> 6;
  const int li = l & 15, g = l >> 4;
  const int dd = blockIdx.x;
  const int bh = (dd & 7) + ((dd >> 3) & 7) * 8;
  const int qt = 15 - (dd >> 6);
  const int b = bh >> 4, hh = bh & 15;
  const size_t plane = (size_t)2048 * 64;
  const unsigned short* Qg  = qkv + (size_t)bh * plane;
  const unsigned short* Kg  = qkv + ((size_t)64 + bh) * plane;
  const unsigned short* VTg = qkv + ((size_t)128 + bh) * plane;  // [64 d][2048 t]
  const int q0 = qt * 128;
  const int nkt = 2 * qt + 2;

  // ---- Q fragments in registers (wave-private rows; already scaled) ----
  bf16x8 bq[2][2];
#pragma unroll
  for (int qB = 0; qB < 2; ++qB)
#pragma unroll
    for (int ks = 0; ks < 2; ++ks) {
      int cc = ks * 4 + g;
      bq[qB][ks] = *reinterpret_cast<const bf16x8*>(
          Qg + (size_t)(q0 + w * 32 + qB * 16 + li) * 64 + cc * 8);
    }

  auto stageK = [&](int kt, int buf) {
#pragma unroll
    for (int it = 0; it < 2; ++it) {
      int c = it * 4 + w;
      int X = c * 1024 + l * 16;
      int row = X >> 7, sl = (X >> 4) & 7;
      gload16(Kg + (size_t)(kt * 64 + row) * 64 + ((sl ^ (row & 7)) * 8),
              (char*)Ks[buf] + c * 1024);
    }
  };
  auto stageVT = [&](int kt, int buf) {
#pragma unroll
    for (int it = 0; it < 2; ++it) {
      int c = it * 4 + w;
      int X = c * 1024 + l * 16;
      int row = X >> 7, sl = (X >> 4) & 7;   // row = d
      gload16(VTg + (size_t)row * 2048 + kt * 64 + ((sl ^ (row & 7)) * 8),
              (char*)VsT[buf] + c * 1024);
    }
  };

  auto computeS = [&](int buf, f32x4 s[4][2]) {
#pragma unroll
    for (int ks = 0; ks < 2; ++ks) {
      bf16x8 ak[4];
      int cc = ks * 4 + g;
#pragma unroll
      for (int kA = 0; kA < 4; ++kA) {
        int kr = kA * 16 + li;
        ak[kA] = *reinterpret_cast<const bf16x8*>(Ks[buf] + kr * 64 + ((cc ^ (kr & 7)) * 8));
      }
#pragma unroll
      for (int kA = 0; kA < 4; ++kA)
#pragma unroll
        for (int qB = 0; qB < 2; ++qB)
          s[kA][qB] = mfma16(ak[kA], bq[qB][ks], s[kA][qB]);
    }
  };

  // ---- pass 1: row denominators (m = 0) ----
  float lsum[2] = {0.f, 0.f};
  stageK(0, 0);
  for (int kt = 0; kt < nkt; ++kt) {
    __syncthreads();
    if (kt + 1 < nkt) stageK(kt + 1, (kt + 1) & 1);
    f32x4 s[4][2] = {};
    computeS(kt & 1, s);
    const bool dg = (kt >= 2 * qt);
#pragma unroll
    for (int qB = 0; qB < 2; ++qB) {
      int qg = q0 + w * 32 + qB * 16 + li;
      float a = 0.f;
#pragma unroll
      for (int kA = 0; kA < 4; ++kA)
#pragma unroll
        for (int r = 0; r < 4; ++r) {
          float e = xexp2(s[kA][qB][r]);
          if (dg) { int k = kt * 64 + kA * 16 + g * 4 + r; e = (k <= qg) ? e : 0.f; }
          a += e;
        }
      lsum[qB] += a;
    }
  }

  float linv[2];
#pragma unroll
  for (int qB = 0; qB < 2; ++qB) {
    float v = lsum[qB];
    v += __shfl_xor(v, 16, 64);
    v += __shfl_xor(v, 32, 64);
    linv[qB] = 1.0f / v;
  }

  // ---- pass 2: attnW stores + O = P@V, counted-vmcnt pipeline ----
  __syncthreads();  // pass-1 Ks reads complete before restage
  stageK(0, 0);
  stageVT(0, 0);
  asm volatile("" ::: "memory");
  asm volatile("s_waitcnt vmcnt(0)" ::: "memory");
  asm volatile("s_barrier" ::: "memory");

  f32x4 o[2][4] = {};
  int cb = 0;
  unsigned short* PsW = &Ps[w][0];

  for (int kt = 0; kt < nkt; ++kt) {
    const int nb = cb ^ 1;
    if (kt + 1 < nkt) { stageK(kt + 1, nb); stageVT(kt + 1, nb); }
    asm volatile("" ::: "memory");  // pin gload issue before stores

    f32x4 s[4][2] = {};
    computeS(cb, s);

    const bool dg = (kt >= 2 * qt);
#pragma unroll
    for (int kA = 0; kA < 4; ++kA)
#pragma unroll
      for (int qB = 0; qB < 2; ++qB) {
        int qg = q0 + w * 32 + qB * 16 + li;
        f32x4 e;
#pragma unroll
        for (int r = 0; r < 4; ++r) {
          float v = xexp2(s[kA][qB][r]) * linv[qB];
          if (dg) { int k = kt * 64 + kA * 16 + g * 4 + r; v = (k <= qg) ? v : 0.f; }
          e[r] = v;
        }
        __builtin_nontemporal_store(e, reinterpret_cast<f32x4*>(
            attnW + ((size_t)bh * 2048 + qg) * 2048 + kt * 64 + kA * 16 + g * 4));
        uint2 pk;
        pk.x = pkbf(e[0], e[1]);
        pk.y = pkbf(e[2], e[3]);
        int qr = qB * 16 + li;
        *reinterpret_cast<uint2*>((char*)PsW + qr * 128 + ((kA * 32 + g * 8) ^ ((qr & 7) << 4))) = pk;
      }

    __builtin_amdgcn_wave_barrier();  // Ps wave-private RAW: pin schedule

    // O^T += V^T x P^T
#pragma unroll
    for (int ks = 0; ks < 2; ++ks) {
      int cc = ks * 4 + g;
      bf16x8 av[4], bp[2];
#pragma unroll
      for (int df = 0; df < 4; ++df) {
        int dr = df * 16 + li;
        av[df] = *reinterpret_cast<const bf16x8*>(VsT[cb] + dr * 64 + ((cc ^ (dr & 7)) * 8));
      }
#pragma unroll
      for (int qB = 0; qB < 2; ++qB) {
        int qr = qB * 16 + li;
        bp[qB] = *reinterpret_cast<const bf16x8*>((const char*)PsW + qr * 128 + ((ks * 64 + g * 16) ^ ((qr & 7) << 4)));
      }
#pragma unroll
      for (int qB = 0; qB < 2; ++qB)
#pragma unroll
        for (int df = 0; df < 4; ++df)
          o[qB][df] = mfma16(av[df], bp[qB], o[qB][df]);
    }

    // retire: prev-tile stores + this tile's 4 gloads; leave this tile's 8 stores in flight
    asm volatile("s_waitcnt vmcnt(8)" ::: "memory");
    asm volatile("s_barrier" ::: "memory");
    cb = nb;
  }

  // ---- O store: lane holds q = qB*16+li, d = df*16 + g*4 + r ----
#pragma unroll
  for (int qB = 0; qB < 2; ++qB) {
    int qg = q0 + w * 32 + qB * 16 + li;
#pragma unroll
    for (int df = 0; df < 4; ++df) {
      ushort4 ov;
      ov.x = f2bf(o[qB][df][0]);
      ov.y = f2bf(o[qB][df][1]);
      ov.z = f2bf(o[qB][df][2]);
      ov.w = f2bf(o[qB][df][3]);
      *reinterpret_cast<ushort4*>(Ob + ((size_t)b * 2048 + qg) * 1024 + hh * 64 + df * 16 + g * 4) = ov;
    }
  }

  // ---- zero-fill masked-out columns (cols >= 128*(qt+1)) ----
  {
    int col0 = 128 * (qt + 1);
    int nch = (2048 - col0) >> 2;
    f32x4 z = {0.f, 0.f, 0.f, 0.f};
    for (int row = 0; row < 128; ++row) {
      size_t base = ((size_t)bh * 2048 + (q0 + row)) * 2048 + col0;
      for (int c = tid; c < nch; c += 256)
        __builtin_nontemporal_store(z, reinterpret_cast<f32x4*>(attnW + base + (size_t)c * 4));
    }
  }
}

extern "C" void kernel_launch(void* const* d_in, const int* in_sizes, int n_in,
                              void* d_out, int out_size, void* d_ws, size_t ws_size,
                              hipStream_t stream) {
  const float* x  = (const float*)d_in[0];
  const float* w1 = (const float*)d_in[1];
  const float* b1 = (const float*)d_in[2];
  const float* w2 = (const float*)d_in[3];
  const float* b2 = (const float*)d_in[4];
  float* out = (float*)d_out;
  float* attnW = out + (size_t)8192 * 1024;

  unsigned short* xb   = (unsigned short*)d_ws;
  unsigned short* w1b  = xb + (size_t)8192 * 1024;
  unsigned short* w2b  = w1b + (size_t)3072 * 1024;
  unsigned short* qkvb = w2b + (size_t)1024 * 1024;
  unsigned short* ob   = qkvb + (size_t)3 * 8192 * 1024;

  f2b_kernel<<<1024, 256, 0, stream>>>(x, xb, 8192 * 1024);
  f2b_kernel<<<512, 256, 0, stream>>>(w1, w1b, 3072 * 1024);
  f2b_kernel<<<256, 256, 0, stream>>>(w2, w2b, 1024 * 1024);

  gemm_bt<1><<<dim3(64, 24), 256, 0, stream>>>(xb, w1b, b1, qkvb, 8192, 3072, 1024);

  attn_kernel<<<1024, 256, 0, stream>>>(qkvb, attnW, ob);

  gemm_bt<0><<<dim3(64, 8), 256, 0, stream>>>(ob, w2b, b2, out, 8192, 1024, 1024);
}

// Round 8
// 459.541 us; speedup vs baseline: 1.0997x; 1.0226x over previous
//
#include <hip/hip_runtime.h>

typedef __bf16 bf16x8 __attribute__((ext_vector_type(8)));
typedef float f32x4 __attribute__((ext_vector_type(4)));
typedef int i32x4 __attribute__((ext_vector_type(4)));

#define DEV __device__ __forceinline__
#define AS1 __attribute__((address_space(1)))
#define AS3 __attribute__((address_space(3)))

DEV unsigned short f2bf(float f) {
  union { float f; unsigned u; } x; x.f = f;
  unsigned r = x.u + 0x7fffu + ((x.u >> 16) & 1u);
  return (unsigned short)(r >> 16);
}

DEV unsigned pkbf(float a, float b) {  // packs {lo=a, hi=b} as 2x bf16 (RNE)
  unsigned r;
  asm("v_cvt_pk_bf16_f32 %0, %1, %2" : "=v"(r) : "v"(a), "v"(b));
  return r;
}

DEV f32x4 mfma16(bf16x8 a, bf16x8 b, f32x4 c) {
  return __builtin_amdgcn_mfma_f32_16x16x32_bf16(a, b, c, 0, 0, 0);
}

#if __has_builtin(__builtin_amdgcn_exp2f)
DEV float xexp2(float x) { return __builtin_amdgcn_exp2f(x); }
#else
DEV float xexp2(float x) { return __expf(x * 0.6931471805599453f); }
#endif

DEV void gload16(const void* g, void* lds) {
  __builtin_amdgcn_global_load_lds((const AS1 void*)g, (AS3 void*)lds, 16, 0, 0);
}

// ---------------- fp32 -> bf16 conversion ----------------
__global__ void f2b_kernel(const float* __restrict__ src, unsigned short* __restrict__ dst, int n) {
  int i = (blockIdx.x * blockDim.x + threadIdx.x) * 4;
  int stride = gridDim.x * blockDim.x * 4;
  for (; i < n; i += stride) {
    float4 v = *reinterpret_cast<const float4*>(src + i);
    ushort4 o;
    o.x = f2bf(v.x); o.y = f2bf(v.y); o.z = f2bf(v.z); o.w = f2bf(v.w);
    *reinterpret_cast<ushort4*>(dst + i) = o;
  }
}

// ---------------- GEMM (m97 structure): C[M,N] = A[M,K] * B[N,K]^T + bias ----------------
// EPI 0: fp32 row-major [M][N].
// EPI 1: qkv scatter. Q (s=0): [bh][t][64] bf16, PRE-SCALED by 0.125*log2(e).
//        K (s=1): [64+bh][t][64].  V (s=2): TRANSPOSED [128+bh][64 d][2048 t].
template <int EPI>
__global__ __launch_bounds__(256, 2)
void gemm_bt(const unsigned short* __restrict__ A, const unsigned short* __restrict__ B,
             const float* __restrict__ bias, void* __restrict__ outv,
             int M, int N, int K) {
  __shared__ __align__(16) unsigned short As[128 * 64];
  __shared__ __align__(16) unsigned short Bs[128 * 64];
  const int tid = threadIdx.x;
  const int l = tid & 63, w = tid >> 6;
  const int wr = w >> 1, wc = w & 1;
  const int tm = blockIdx.x * 128, tn = blockIdx.y * 128;
  const int lr = l >> 3, lc = (l & 7) * 8;

  f32x4 acc[4][4] = {};

  for (int kt = 0; kt < K; kt += 64) {
#pragma unroll
    for (int i = 0; i < 4; ++i) {
      int c = i * 4 + w;
      gload16(A + (size_t)(tm + c * 8 + lr) * K + kt + lc, (char*)As + c * 1024);
    }
#pragma unroll
    for (int i = 0; i < 4; ++i) {
      int c = i * 4 + w;
      gload16(B + (size_t)(tn + c * 8 + lr) * K + kt + lc, (char*)Bs + c * 1024);
    }
    __syncthreads();
#pragma unroll
    for (int ks = 0; ks < 2; ++ks) {
      int ko = ks * 32 + (l >> 4) * 8;
      bf16x8 af[4], bfr[4];
#pragma unroll
      for (int i = 0; i < 4; ++i) {
        af[i]  = *reinterpret_cast<const bf16x8*>(As + (wr * 64 + i * 16 + (l & 15)) * 64 + ko);
        bfr[i] = *reinterpret_cast<const bf16x8*>(Bs + (wc * 64 + i * 16 + (l & 15)) * 64 + ko);
      }
#pragma unroll
      for (int mi = 0; mi < 4; ++mi)
#pragma unroll
        for (int ni = 0; ni < 4; ++ni)
          acc[mi][ni] = mfma16(af[mi], bfr[ni], acc[mi][ni]);
    }
    __syncthreads();
  }

#pragma unroll
  for (int ni = 0; ni < 4; ++ni) {
    int n = tn + wc * 64 + ni * 16 + (l & 15);
    float bv = bias[n];
    if (EPI == 0) {
      float* out = (float*)outv;
#pragma unroll
      for (int mi = 0; mi < 4; ++mi)
#pragma unroll
        for (int r = 0; r < 4; ++r) {
          int m = tm + wr * 64 + mi * 16 + (l >> 4) * 4 + r;
          out[(size_t)m * N + n] = acc[mi][ni][r] + bv;
        }
    } else {
      unsigned short* out = (unsigned short*)outv;
      int s = n >> 10, rem = n & 1023, h = rem >> 6, d = rem & 63;
      if (s == 2) {
        // V transposed: [128 + bh][d][t], 4 consecutive t per lane -> ushort4
#pragma unroll
        for (int mi = 0; mi < 4; ++mi) {
          int m = tm + wr * 64 + mi * 16 + (l >> 4) * 4;
          int bb = m >> 11, t = m & 2047;
          ushort4 pv;
          pv.x = f2bf(acc[mi][ni][0] + bv);
          pv.y = f2bf(acc[mi][ni][1] + bv);
          pv.z = f2bf(acc[mi][ni][2] + bv);
          pv.w = f2bf(acc[mi][ni][3] + bv);
          size_t off = ((size_t)(128 + bb * 16 + h)) * 131072 + (size_t)d * 2048 + t;
          *reinterpret_cast<ushort4*>(out + off) = pv;
        }
      } else {
        const float sc = (s == 0) ? 0.1803368801f : 1.0f;  // fold 0.125*log2(e) into Q
#pragma unroll
        for (int mi = 0; mi < 4; ++mi)
#pragma unroll
          for (int r = 0; r < 4; ++r) {
            int m = tm + wr * 64 + mi * 16 + (l >> 4) * 4 + r;
            int bb = m >> 11, t = m & 2047;
            size_t off = ((((size_t)s * 4 + bb) * 16 + h) * 2048 + t) * 64 + d;
            out[off] = f2bf((acc[mi][ni][r] + bv) * sc);
          }
      }
    }
  }
}

// ---------------- Attention ----------------
// 1024 blocks 1-D, XCD-chunked. 4 waves x 32 q-rows. Q in registers (pre-scaled).
// Pass 1: 3-deep K ring + counted vmcnt(2) per tile (hide gload latency).
// Pass 2: K/V^T double-buffer + counted vmcnt(8) (attnW stores ride through next tile).
// LDS: one 48KB arena; pass-1 ring aliases pass-2 K/V buffers (phases sync-separated).
__global__ __launch_bounds__(256, 3)
void attn_kernel(const unsigned short* __restrict__ qkv, float* __restrict__ attnW,
                 unsigned short* __restrict__ Ob) {
  __shared__ __align__(16) char smem[49152];
  // pass 1: ring bufs at smem + {0,1,2}*8192
  // pass 2: Ks dbuf at smem + {0,1}*8192; VsT dbuf at smem + 16384 + {0,1}*8192;
  //         Ps per wave at smem + 32768 + w*4096

  const int tid = threadIdx.x, l = tid & 63, w = tid >> 6;
  const int li = l & 15, g = l >> 4;
  const int dd = blockIdx.x;
  const int bh = (dd & 7) + ((dd >> 3) & 7) * 8;
  const int qt = 15 - (dd >> 6);
  const int b = bh >> 4, hh = bh & 15;
  const size_t plane = (size_t)2048 * 64;
  const unsigned short* Qg  = qkv + (size_t)bh * plane;
  const unsigned short* Kg  = qkv + ((size_t)64 + bh) * plane;
  const unsigned short* VTg = qkv + ((size_t)128 + bh) * plane;  // [64 d][2048 t]
  const int q0 = qt * 128;
  const int nkt = 2 * qt + 2;

  // ---- Q fragments in registers (wave-private rows; already scaled) ----
  bf16x8 bq[2][2];
#pragma unroll
  for (int qB = 0; qB < 2; ++qB)
#pragma unroll
    for (int ks = 0; ks < 2; ++ks) {
      int cc = ks * 4 + g;
      bq[qB][ks] = *reinterpret_cast<const bf16x8*>(
          Qg + (size_t)(q0 + w * 32 + qB * 16 + li) * 64 + cc * 8);
    }

  // stage one 64x64 bf16 K-tile into arena slot `base` (XOR-swizzled source)
  auto stageK = [&](int kt, char* base) {
#pragma unroll
    for (int it = 0; it < 2; ++it) {
      int c = it * 4 + w;
      int X = c * 1024 + l * 16;
      int row = X >> 7, sl = (X >> 4) & 7;
      gload16(Kg + (size_t)(kt * 64 + row) * 64 + ((sl ^ (row & 7)) * 8), base + c * 1024);
    }
  };
  auto stageVT = [&](int kt, char* base) {
#pragma unroll
    for (int it = 0; it < 2; ++it) {
      int c = it * 4 + w;
      int X = c * 1024 + l * 16;
      int row = X >> 7, sl = (X >> 4) & 7;   // row = d
      gload16(VTg + (size_t)row * 2048 + kt * 64 + ((sl ^ (row & 7)) * 8), base + c * 1024);
    }
  };

  auto computeS = [&](const char* base, f32x4 s[4][2]) {
    const unsigned short* Kp = (const unsigned short*)base;
#pragma unroll
    for (int ks = 0; ks < 2; ++ks) {
      bf16x8 ak[4];
      int cc = ks * 4 + g;
#pragma unroll
      for (int kA = 0; kA < 4; ++kA) {
        int kr = kA * 16 + li;
        ak[kA] = *reinterpret_cast<const bf16x8*>(Kp + kr * 64 + ((cc ^ (kr & 7)) * 8));
      }
#pragma unroll
      for (int kA = 0; kA < 4; ++kA)
#pragma unroll
        for (int qB = 0; qB < 2; ++qB)
          s[kA][qB] = mfma16(ak[kA], bq[qB][ks], s[kA][qB]);
    }
  };

  // ---- pass 1: row denominators (m = 0), 3-ring + counted vmcnt ----
  float lsum[2] = {0.f, 0.f};
  {
    int i0 = 0, i1 = 1, i2 = 2;
    stageK(0, smem);
    stageK(1, smem + 8192);
    asm volatile("s_waitcnt vmcnt(2)" ::: "memory");
    asm volatile("s_barrier" ::: "memory");
    for (int kt = 0; kt < nkt; ++kt) {
      const bool pf = (kt + 2 < nkt);
      if (pf) stageK(kt + 2, smem + i2 * 8192);
      f32x4 s[4][2] = {};
      computeS(smem + i0 * 8192, s);
      const bool dg = (kt >= 2 * qt);
#pragma unroll
      for (int qB = 0; qB < 2; ++qB) {
        int qg = q0 + w * 32 + qB * 16 + li;
        float a = 0.f;
#pragma unroll
        for (int kA = 0; kA < 4; ++kA)
#pragma unroll
          for (int r = 0; r < 4; ++r) {
            float e = xexp2(s[kA][qB][r]);
            if (dg) { int k = kt * 64 + kA * 16 + g * 4 + r; e = (k <= qg) ? e : 0.f; }
            a += e;
          }
        lsum[qB] += a;
      }
      if (pf) asm volatile("s_waitcnt vmcnt(2)" ::: "memory");
      else    asm volatile("s_waitcnt vmcnt(0)" ::: "memory");
      asm volatile("s_barrier" ::: "memory");
      int t = i0; i0 = i1; i1 = i2; i2 = t;
    }
  }

  float linv[2];
#pragma unroll
  for (int qB = 0; qB < 2; ++qB) {
    float v = lsum[qB];
    v += __shfl_xor(v, 16, 64);
    v += __shfl_xor(v, 32, 64);
    linv[qB] = 1.0f / v;
  }

  // ---- pass 2: attnW stores + O = P@V, counted-vmcnt pipeline ----
  __syncthreads();  // full drain before arena re-carve
  char* KsB  = smem;           // dbuf {0,1}*8192
  char* VsB  = smem + 16384;   // dbuf {0,1}*8192
  unsigned short* PsW = (unsigned short*)(smem + 32768 + w * 4096);

  stageK(0, KsB);
  stageVT(0, VsB);
  asm volatile("" ::: "memory");
  asm volatile("s_waitcnt vmcnt(0)" ::: "memory");
  asm volatile("s_barrier" ::: "memory");

  f32x4 o[2][4] = {};
  int cb = 0;

  for (int kt = 0; kt < nkt; ++kt) {
    const int nb = cb ^ 1;
    if (kt + 1 < nkt) { stageK(kt + 1, KsB + nb * 8192); stageVT(kt + 1, VsB + nb * 8192); }
    asm volatile("" ::: "memory");  // pin gload issue before stores

    f32x4 s[4][2] = {};
    computeS(KsB + cb * 8192, s);

    const bool dg = (kt >= 2 * qt);
#pragma unroll
    for (int kA = 0; kA < 4; ++kA)
#pragma unroll
      for (int qB = 0; qB < 2; ++qB) {
        int qg = q0 + w * 32 + qB * 16 + li;
        f32x4 e;
#pragma unroll
        for (int r = 0; r < 4; ++r) {
          float v = xexp2(s[kA][qB][r]) * linv[qB];
          if (dg) { int k = kt * 64 + kA * 16 + g * 4 + r; v = (k <= qg) ? v : 0.f; }
          e[r] = v;
        }
        __builtin_nontemporal_store(e, reinterpret_cast<f32x4*>(
            attnW + ((size_t)bh * 2048 + qg) * 2048 + kt * 64 + kA * 16 + g * 4));
        uint2 pk;
        pk.x = pkbf(e[0], e[1]);
        pk.y = pkbf(e[2], e[3]);
        int qr = qB * 16 + li;
        *reinterpret_cast<uint2*>((char*)PsW + qr * 128 + ((kA * 32 + g * 8) ^ ((qr & 7) << 4))) = pk;
      }

    __builtin_amdgcn_wave_barrier();  // Ps wave-private RAW: pin schedule

    // O^T += V^T x P^T
    const unsigned short* Vp = (const unsigned short*)(VsB + cb * 8192);
#pragma unroll
    for (int ks = 0; ks < 2; ++ks) {
      int cc = ks * 4 + g;
      bf16x8 av[4], bp[2];
#pragma unroll
      for (int df = 0; df < 4; ++df) {
        int dr = df * 16 + li;
        av[df] = *reinterpret_cast<const bf16x8*>(Vp + dr * 64 + ((cc ^ (dr & 7)) * 8));
      }
#pragma unroll
      for (int qB = 0; qB < 2; ++qB) {
        int qr = qB * 16 + li;
        bp[qB] = *reinterpret_cast<const bf16x8*>((const char*)PsW + qr * 128 + ((ks * 64 + g * 16) ^ ((qr & 7) << 4)));
      }
#pragma unroll
      for (int qB = 0; qB < 2; ++qB)
#pragma unroll
        for (int df = 0; df < 4; ++df)
          o[qB][df] = mfma16(av[df], bp[qB], o[qB][df]);
    }

    // retire: prev-tile stores + this tile's 4 gloads; leave this tile's 8 stores in flight
    asm volatile("s_waitcnt vmcnt(8)" ::: "memory");
    asm volatile("s_barrier" ::: "memory");
    cb = nb;
  }

  // ---- O store: lane holds q = qB*16+li, d = df*16 + g*4 + r (O^T layout) ----
#pragma unroll
  for (int qB = 0; qB < 2; ++qB) {
    int qg = q0 + w * 32 + qB * 16 + li;
#pragma unroll
    for (int df = 0; df < 4; ++df) {
      ushort4 ov;
      ov.x = f2bf(o[qB][df][0]);
      ov.y = f2bf(o[qB][df][1]);
      ov.z = f2bf(o[qB][df][2]);
      ov.w = f2bf(o[qB][df][3]);
      *reinterpret_cast<ushort4*>(Ob + ((size_t)b * 2048 + qg) * 1024 + hh * 64 + df * 16 + g * 4) = ov;
    }
  }

  // ---- zero-fill masked-out columns (cols >= 128*(qt+1)) ----
  {
    int col0 = 128 * (qt + 1);
    int nch = (2048 - col0) >> 2;
    f32x4 z = {0.f, 0.f, 0.f, 0.f};
    for (int row = 0; row < 128; ++row) {
      size_t base = ((size_t)bh * 2048 + (q0 + row)) * 2048 + col0;
      for (int c = tid; c < nch; c += 256)
        __builtin_nontemporal_store(z, reinterpret_cast<f32x4*>(attnW + base + (size_t)c * 4));
    }
  }
}

extern "C" void kernel_launch(void* const* d_in, const int* in_sizes, int n_in,
                              void* d_out, int out_size, void* d_ws, size_t ws_size,
                              hipStream_t stream) {
  const float* x  = (const float*)d_in[0];
  const float* w1 = (const float*)d_in[1];
  const float* b1 = (const float*)d_in[2];
  const float* w2 = (const float*)d_in[3];
  const float* b2 = (const float*)d_in[4];
  float* out = (float*)d_out;
  float* attnW = out + (size_t)8192 * 1024;

  unsigned short* xb   = (unsigned short*)d_ws;
  unsigned short* w1b  = xb + (size_t)8192 * 1024;
  unsigned short* w2b  = w1b + (size_t)3072 * 1024;
  unsigned short* qkvb = w2b + (size_t)1024 * 1024;
  unsigned short* ob   = qkvb + (size_t)3 * 8192 * 1024;

  f2b_kernel<<<1024, 256, 0, stream>>>(x, xb, 8192 * 1024);
  f2b_kernel<<<512, 256, 0, stream>>>(w1, w1b, 3072 * 1024);
  f2b_kernel<<<256, 256, 0, stream>>>(w2, w2b, 1024 * 1024);

  gemm_bt<1><<<dim3(64, 24), 256, 0, stream>>>(xb, w1b, b1, qkvb, 8192, 3072, 1024);

  attn_kernel<<<1024, 256, 0, stream>>>(qkvb, attnW, ob);

  gemm_bt<0><<<dim3(64, 8), 256, 0, stream>>>(ob, w2b, b2, out, 8192, 1024, 1024);
}

// Round 10
// 454.524 us; speedup vs baseline: 1.1118x; 1.0110x over previous
//
#include <hip/hip_runtime.h>

typedef __bf16 bf16x8 __attribute__((ext_vector_type(8)));
typedef float f32x4 __attribute__((ext_vector_type(4)));
typedef int i32x4 __attribute__((ext_vector_type(4)));

#define DEV __device__ __forceinline__
#define AS1 __attribute__((address_space(1)))
#define AS3 __attribute__((address_space(3)))

DEV unsigned short f2bf(float f) {
  union { float f; unsigned u; } x; x.f = f;
  unsigned r = x.u + 0x7fffu + ((x.u >> 16) & 1u);
  return (unsigned short)(r >> 16);
}

DEV unsigned pkbf(float a, float b) {  // packs {lo=a, hi=b} as 2x bf16 (RNE)
  unsigned r;
  asm("v_cvt_pk_bf16_f32 %0, %1, %2" : "=v"(r) : "v"(a), "v"(b));
  return r;
}

DEV f32x4 mfma16(bf16x8 a, bf16x8 b, f32x4 c) {
  return __builtin_amdgcn_mfma_f32_16x16x32_bf16(a, b, c, 0, 0, 0);
}

#if __has_builtin(__builtin_amdgcn_exp2f)
DEV float xexp2(float x) { return __builtin_amdgcn_exp2f(x); }
#else
DEV float xexp2(float x) { return __expf(x * 0.6931471805599453f); }
#endif

DEV void gload16(const void* g, void* lds) {
  __builtin_amdgcn_global_load_lds((const AS1 void*)g, (AS3 void*)lds, 16, 0, 0);
}

// ---------------- fp32 -> bf16 conversion ----------------
__global__ void f2b_kernel(const float* __restrict__ src, unsigned short* __restrict__ dst, int n) {
  int i = (blockIdx.x * blockDim.x + threadIdx.x) * 4;
  int stride = gridDim.x * blockDim.x * 4;
  for (; i < n; i += stride) {
    float4 v = *reinterpret_cast<const float4*>(src + i);
    ushort4 o;
    o.x = f2bf(v.x); o.y = f2bf(v.y); o.z = f2bf(v.z); o.w = f2bf(v.w);
    *reinterpret_cast<ushort4*>(dst + i) = o;
  }
}

// ---------------- GEMM (m97 structure): C[M,N] = A[M,K] * B[N,K]^T + bias ----------------
// EPI 0: fp32 row-major [M][N].
// EPI 1: qkv scatter. Q (s=0): [bh][t][64] bf16, PRE-SCALED by 0.125*log2(e).
//        K (s=1): [64+bh][t][64].  V (s=2): TRANSPOSED [128+bh][64 d][2048 t].
template <int EPI>
__global__ __launch_bounds__(256, 3)
void gemm_bt(const unsigned short* __restrict__ A, const unsigned short* __restrict__ B,
             const float* __restrict__ bias, void* __restrict__ outv,
             int M, int N, int K) {
  __shared__ __align__(16) unsigned short As[128 * 64];
  __shared__ __align__(16) unsigned short Bs[128 * 64];
  const int tid = threadIdx.x;
  const int l = tid & 63, w = tid >> 6;
  const int wr = w >> 1, wc = w & 1;
  const int tm = blockIdx.x * 128, tn = blockIdx.y * 128;
  const int lr = l >> 3, lc = (l & 7) * 8;

  f32x4 acc[4][4] = {};

  for (int kt = 0; kt < K; kt += 64) {
#pragma unroll
    for (int i = 0; i < 4; ++i) {
      int c = i * 4 + w;
      gload16(A + (size_t)(tm + c * 8 + lr) * K + kt + lc, (char*)As + c * 1024);
    }
#pragma unroll
    for (int i = 0; i < 4; ++i) {
      int c = i * 4 + w;
      gload16(B + (size_t)(tn + c * 8 + lr) * K + kt + lc, (char*)Bs + c * 1024);
    }
    __syncthreads();
#pragma unroll
    for (int ks = 0; ks < 2; ++ks) {
      int ko = ks * 32 + (l >> 4) * 8;
      bf16x8 af[4], bfr[4];
#pragma unroll
      for (int i = 0; i < 4; ++i) {
        af[i]  = *reinterpret_cast<const bf16x8*>(As + (wr * 64 + i * 16 + (l & 15)) * 64 + ko);
        bfr[i] = *reinterpret_cast<const bf16x8*>(Bs + (wc * 64 + i * 16 + (l & 15)) * 64 + ko);
      }
#pragma unroll
      for (int mi = 0; mi < 4; ++mi)
#pragma unroll
        for (int ni = 0; ni < 4; ++ni)
          acc[mi][ni] = mfma16(af[mi], bfr[ni], acc[mi][ni]);
    }
    __syncthreads();
  }

#pragma unroll
  for (int ni = 0; ni < 4; ++ni) {
    int n = tn + wc * 64 + ni * 16 + (l & 15);
    float bv = bias[n];
    if (EPI == 0) {
      float* out = (float*)outv;
#pragma unroll
      for (int mi = 0; mi < 4; ++mi)
#pragma unroll
        for (int r = 0; r < 4; ++r) {
          int m = tm + wr * 64 + mi * 16 + (l >> 4) * 4 + r;
          out[(size_t)m * N + n] = acc[mi][ni][r] + bv;
        }
    } else {
      unsigned short* out = (unsigned short*)outv;
      int s = n >> 10, rem = n & 1023, h = rem >> 6, d = rem & 63;
      if (s == 2) {
        // V transposed: [128 + bh][d][t], 4 consecutive t per lane -> ushort4
#pragma unroll
        for (int mi = 0; mi < 4; ++mi) {
          int m = tm + wr * 64 + mi * 16 + (l >> 4) * 4;
          int bb = m >> 11, t = m & 2047;
          ushort4 pv;
          pv.x = f2bf(acc[mi][ni][0] + bv);
          pv.y = f2bf(acc[mi][ni][1] + bv);
          pv.z = f2bf(acc[mi][ni][2] + bv);
          pv.w = f2bf(acc[mi][ni][3] + bv);
          size_t off = ((size_t)(128 + bb * 16 + h)) * 131072 + (size_t)d * 2048 + t;
          *reinterpret_cast<ushort4*>(out + off) = pv;
        }
      } else {
        const float sc = (s == 0) ? 0.1803368801f : 1.0f;  // fold 0.125*log2(e) into Q
#pragma unroll
        for (int mi = 0; mi < 4; ++mi)
#pragma unroll
          for (int r = 0; r < 4; ++r) {
            int m = tm + wr * 64 + mi * 16 + (l >> 4) * 4 + r;
            int bb = m >> 11, t = m & 2047;
            size_t off = ((((size_t)s * 4 + bb) * 16 + h) * 2048 + t) * 64 + d;
            out[off] = f2bf((acc[mi][ni][r] + bv) * sc);
          }
      }
    }
  }
}

// ---------------- Attention ----------------
// 1024 blocks 1-D, XCD-chunked. 4 waves x 32 q-rows. Q in registers (pre-scaled).
// Pass 1: BK=128 2-ring (half the barriers); vmcnt(0) waits on loads issued a
//         full 128-tile earlier -> latency hidden.
// Pass 2: K/V^T double-buffer, prefetch kt+1; per-wave vmcnt(8) then s_barrier
//         (cross-wave visibility via barrier ONLY); attnW stores ride 1 tile.
// LDS arena 48 KB; pass-1 ring aliases pass-2 carve (phases sync-separated).
__global__ __launch_bounds__(256, 3)
void attn_kernel(const unsigned short* __restrict__ qkv, float* __restrict__ attnW,
                 unsigned short* __restrict__ Ob) {
  __shared__ __align__(16) char smem[49152];
  // pass 1: ring {0,1}*16384
  // pass 2: Ks dbuf {0,1}*8192; VsT dbuf 16384+{0,1}*8192; Ps @32768 + w*4096

  const int tid = threadIdx.x, l = tid & 63, w = tid >> 6;
  const int li = l & 15, g = l >> 4;
  const int dd = blockIdx.x;
  const int bh = (dd & 7) + ((dd >> 3) & 7) * 8;
  const int qt = 15 - (dd >> 6);
  const int b = bh >> 4, hh = bh & 15;
  const size_t plane = (size_t)2048 * 64;
  const unsigned short* Qg  = qkv + (size_t)bh * plane;
  const unsigned short* Kg  = qkv + ((size_t)64 + bh) * plane;
  const unsigned short* VTg = qkv + ((size_t)128 + bh) * plane;  // [64 d][2048 t]
  const int q0 = qt * 128;
  const int nkt = 2 * qt + 2;

  // ---- Q fragments in registers (wave-private rows; already scaled) ----
  bf16x8 bq[2][2];
#pragma unroll
  for (int qB = 0; qB < 2; ++qB)
#pragma unroll
    for (int ks = 0; ks < 2; ++ks) {
      int cc = ks * 4 + g;
      bq[qB][ks] = *reinterpret_cast<const bf16x8*>(
          Qg + (size_t)(q0 + w * 32 + qB * 16 + li) * 64 + cc * 8);
    }

  auto stageK = [&](int kt64, char* base) {
#pragma unroll
    for (int it = 0; it < 2; ++it) {
      int c = it * 4 + w;
      int X = c * 1024 + l * 16;
      int row = X >> 7, sl = (X >> 4) & 7;
      gload16(Kg + (size_t)(kt64 * 64 + row) * 64 + ((sl ^ (row & 7)) * 8), base + c * 1024);
    }
  };
  auto stageK128 = [&](int kt128, char* base) {
#pragma unroll
    for (int it = 0; it < 4; ++it) {
      int c = it * 4 + w;
      int X = c * 1024 + l * 16;
      int row = X >> 7, sl = (X >> 4) & 7;
      gload16(Kg + (size_t)(kt128 * 128 + row) * 64 + ((sl ^ (row & 7)) * 8), base + c * 1024);
    }
  };
  auto stageVT = [&](int kt64, char* base) {
#pragma unroll
    for (int it = 0; it < 2; ++it) {
      int c = it * 4 + w;
      int X = c * 1024 + l * 16;
      int row = X >> 7, sl = (X >> 4) & 7;   // row = d
      gload16(VTg + (size_t)row * 2048 + kt64 * 64 + ((sl ^ (row & 7)) * 8), base + c * 1024);
    }
  };

  auto computeS = [&](const char* base, f32x4 s[4][2]) {
    const unsigned short* Kp = (const unsigned short*)base;
#pragma unroll
    for (int ks = 0; ks < 2; ++ks) {
      bf16x8 ak[4];
      int cc = ks * 4 + g;
#pragma unroll
      for (int kA = 0; kA < 4; ++kA) {
        int kr = kA * 16 + li;
        ak[kA] = *reinterpret_cast<const bf16x8*>(Kp + kr * 64 + ((cc ^ (kr & 7)) * 8));
      }
#pragma unroll
      for (int kA = 0; kA < 4; ++kA)
#pragma unroll
        for (int qB = 0; qB < 2; ++qB)
          s[kA][qB] = mfma16(ak[kA], bq[qB][ks], s[kA][qB]);
    }
  };

  // ---- pass 1: row denominators (m = 0), BK=128, 2-ring ----
  float lsum[2] = {0.f, 0.f};
  {
    const int nkt1 = qt + 1;
    stageK128(0, smem);
    asm volatile("s_waitcnt vmcnt(0)" ::: "memory");
    asm volatile("s_barrier" ::: "memory");
    int cb1 = 0;
    for (int kt = 0; kt < nkt1; ++kt) {
      const int nb1 = cb1 ^ 1;
      if (kt + 1 < nkt1) stageK128(kt + 1, smem + nb1 * 16384);
      const bool dg = (kt == qt);
#pragma unroll
      for (int half = 0; half < 2; ++half) {
        f32x4 s[4][2] = {};
        computeS(smem + cb1 * 16384 + half * 8192, s);
#pragma unroll
        for (int qB = 0; qB < 2; ++qB) {
          int qg = q0 + w * 32 + qB * 16 + li;
          float a = 0.f;
#pragma unroll
          for (int kA = 0; kA < 4; ++kA)
#pragma unroll
            for (int r = 0; r < 4; ++r) {
              float e = xexp2(s[kA][qB][r]);
              if (dg) { int k = kt * 128 + half * 64 + kA * 16 + g * 4 + r; e = (k <= qg) ? e : 0.f; }
              a += e;
            }
          lsum[qB] += a;
        }
      }
      asm volatile("s_waitcnt vmcnt(0)" ::: "memory");
      asm volatile("s_barrier" ::: "memory");
      cb1 = nb1;
    }
  }

  float linv[2];
#pragma unroll
  for (int qB = 0; qB < 2; ++qB) {
    float v = lsum[qB];
    v += __shfl_xor(v, 16, 64);
    v += __shfl_xor(v, 32, 64);
    linv[qB] = 1.0f / v;
  }

  // ---- pass 2: attnW stores + O = P@V, K/V dbuf + counted vmcnt (R8-proven) ----
  __syncthreads();  // full drain before arena re-carve
  char* KsB = smem;                       // dbuf {0,1}*8192
  char* VsB = smem + 16384;               // dbuf {0,1}*8192
  unsigned short* PsW = (unsigned short*)(smem + 32768 + w * 4096);

  stageK(0, KsB);
  stageVT(0, VsB);
  asm volatile("" ::: "memory");
  asm volatile("s_waitcnt vmcnt(0)" ::: "memory");
  asm volatile("s_barrier" ::: "memory");

  f32x4 o[2][4] = {};
  int cb = 0;

  for (int kt = 0; kt < nkt; ++kt) {
    const int nb = cb ^ 1;
    if (kt + 1 < nkt) { stageK(kt + 1, KsB + nb * 8192); stageVT(kt + 1, VsB + nb * 8192); }
    asm volatile("" ::: "memory");  // pin gload issue before stores

    f32x4 s[4][2] = {};
    computeS(KsB + cb * 8192, s);

    const bool dg = (kt >= 2 * qt);
#pragma unroll
    for (int kA = 0; kA < 4; ++kA)
#pragma unroll
      for (int qB = 0; qB < 2; ++qB) {
        int qg = q0 + w * 32 + qB * 16 + li;
        f32x4 e;
#pragma unroll
        for (int r = 0; r < 4; ++r) {
          float v = xexp2(s[kA][qB][r]) * linv[qB];
          if (dg) { int k = kt * 64 + kA * 16 + g * 4 + r; v = (k <= qg) ? v : 0.f; }
          e[r] = v;
        }
        __builtin_nontemporal_store(e, reinterpret_cast<f32x4*>(
            attnW + ((size_t)bh * 2048 + qg) * 2048 + kt * 64 + kA * 16 + g * 4));
        uint2 pk;
        pk.x = pkbf(e[0], e[1]);
        pk.y = pkbf(e[2], e[3]);
        int qr = qB * 16 + li;
        *reinterpret_cast<uint2*>((char*)PsW + qr * 128 + ((kA * 32 + g * 8) ^ ((qr & 7) << 4))) = pk;
      }

    __builtin_amdgcn_wave_barrier();  // Ps wave-private RAW: pin schedule

    // O^T += V^T x P^T
    const unsigned short* Vp = (const unsigned short*)(VsB + cb * 8192);
#pragma unroll
    for (int ks = 0; ks < 2; ++ks) {
      int cc = ks * 4 + g;
      bf16x8 av[4], bp[2];
#pragma unroll
      for (int df = 0; df < 4; ++df) {
        int dr = df * 16 + li;
        av[df] = *reinterpret_cast<const bf16x8*>(Vp + dr * 64 + ((cc ^ (dr & 7)) * 8));
      }
#pragma unroll
      for (int qB = 0; qB < 2; ++qB) {
        int qr = qB * 16 + li;
        bp[qB] = *reinterpret_cast<const bf16x8*>((const char*)PsW + qr * 128 + ((ks * 64 + g * 16) ^ ((qr & 7) << 4)));
      }
#pragma unroll
      for (int qB = 0; qB < 2; ++qB)
#pragma unroll
        for (int df = 0; df < 4; ++df)
          o[qB][df] = mfma16(av[df], bp[qB], o[qB][df]);
    }

    // retire: prev-tile stores + this tile's 4 gloads; leave this tile's 8 stores in flight.
    // s_barrier AFTER the wait makes kt+1 staging visible to ALL waves (vmcnt is per-wave).
    asm volatile("s_waitcnt vmcnt(8)" ::: "memory");
    asm volatile("s_barrier" ::: "memory");
    cb = nb;
  }

  // ---- O store: lane holds q = qB*16+li, d = df*16 + g*4 + r (O^T layout) ----
#pragma unroll
  for (int qB = 0; qB < 2; ++qB) {
    int qg = q0 + w * 32 + qB * 16 + li;
#pragma unroll
    for (int df = 0; df < 4; ++df) {
      ushort4 ov;
      ov.x = f2bf(o[qB][df][0]);
      ov.y = f2bf(o[qB][df][1]);
      ov.z = f2bf(o[qB][df][2]);
      ov.w = f2bf(o[qB][df][3]);
      *reinterpret_cast<ushort4*>(Ob + ((size_t)b * 2048 + qg) * 1024 + hh * 64 + df * 16 + g * 4) = ov;
    }
  }

  // ---- zero-fill masked-out columns (cols >= 128*(qt+1)) ----
  {
    int col0 = 128 * (qt + 1);
    int nch = (2048 - col0) >> 2;
    f32x4 z = {0.f, 0.f, 0.f, 0.f};
    for (int row = 0; row < 128; ++row) {
      size_t base = ((size_t)bh * 2048 + (q0 + row)) * 2048 + col0;
      for (int c = tid; c < nch; c += 256)
        __builtin_nontemporal_store(z, reinterpret_cast<f32x4*>(attnW + base + (size_t)c * 4));
    }
  }
}

extern "C" void kernel_launch(void* const* d_in, const int* in_sizes, int n_in,
                              void* d_out, int out_size, void* d_ws, size_t ws_size,
                              hipStream_t stream) {
  const float* x  = (const float*)d_in[0];
  const float* w1 = (const float*)d_in[1];
  const float* b1 = (const float*)d_in[2];
  const float* w2 = (const float*)d_in[3];
  const float* b2 = (const float*)d_in[4];
  float* out = (float*)d_out;
  float* attnW = out + (size_t)8192 * 1024;

  unsigned short* xb   = (unsigned short*)d_ws;
  unsigned short* w1b  = xb + (size_t)8192 * 1024;
  unsigned short* w2b  = w1b + (size_t)3072 * 1024;
  unsigned short* qkvb = w2b + (size_t)1024 * 1024;
  unsigned short* ob   = qkvb + (size_t)3 * 8192 * 1024;

  f2b_kernel<<<1024, 256, 0, stream>>>(x, xb, 8192 * 1024);
  f2b_kernel<<<512, 256, 0, stream>>>(w1, w1b, 3072 * 1024);
  f2b_kernel<<<256, 256, 0, stream>>>(w2, w2b, 1024 * 1024);

  gemm_bt<1><<<dim3(64, 24), 256, 0, stream>>>(xb, w1b, b1, qkvb, 8192, 3072, 1024);

  attn_kernel<<<1024, 256, 0, stream>>>(qkvb, attnW, ob);

  gemm_bt<0><<<dim3(64, 8), 256, 0, stream>>>(ob, w2b, b2, out, 8192, 1024, 1024);
}

// Round 11
// 420.237 us; speedup vs baseline: 1.2025x; 1.0816x over previous
//
#include <hip/hip_runtime.h>

typedef __bf16 bf16x8 __attribute__((ext_vector_type(8)));
typedef float f32x4 __attribute__((ext_vector_type(4)));
typedef int i32x4 __attribute__((ext_vector_type(4)));

#define DEV __device__ __forceinline__
#define AS1 __attribute__((address_space(1)))
#define AS3 __attribute__((address_space(3)))

DEV unsigned short f2bf(float f) {
  union { float f; unsigned u; } x; x.f = f;
  unsigned r = x.u + 0x7fffu + ((x.u >> 16) & 1u);
  return (unsigned short)(r >> 16);
}

DEV unsigned pkbf(float a, float b) {  // packs {lo=a, hi=b} as 2x bf16 (RNE)
  unsigned r;
  asm("v_cvt_pk_bf16_f32 %0, %1, %2" : "=v"(r) : "v"(a), "v"(b));
  return r;
}

DEV f32x4 mfma16(bf16x8 a, bf16x8 b, f32x4 c) {
  return __builtin_amdgcn_mfma_f32_16x16x32_bf16(a, b, c, 0, 0, 0);
}

#if __has_builtin(__builtin_amdgcn_exp2f)
DEV float xexp2(float x) { return __builtin_amdgcn_exp2f(x); }
#else
DEV float xexp2(float x) { return __expf(x * 0.6931471805599453f); }
#endif

DEV void gload16(const void* g, void* lds) {
  __builtin_amdgcn_global_load_lds((const AS1 void*)g, (AS3 void*)lds, 16, 0, 0);
}

// ---------------- fp32 -> bf16 conversion ----------------
__global__ void f2b_kernel(const float* __restrict__ src, unsigned short* __restrict__ dst, int n) {
  int i = (blockIdx.x * blockDim.x + threadIdx.x) * 4;
  int stride = gridDim.x * blockDim.x * 4;
  for (; i < n; i += stride) {
    float4 v = *reinterpret_cast<const float4*>(src + i);
    ushort4 o;
    o.x = f2bf(v.x); o.y = f2bf(v.y); o.z = f2bf(v.z); o.w = f2bf(v.w);
    *reinterpret_cast<ushort4*>(dst + i) = o;
  }
}

// ---------------- GEMM (m97 structure): C[M,N] = A[M,K] * B[N,K]^T + bias ----------------
// EPI 0: fp32 row-major [M][N].
// EPI 1: qkv scatter. Q (s=0): [bh][t][64] bf16, PRE-SCALED by 0.125*log2(e).
//        K (s=1): [64+bh][t][64].  V (s=2): TRANSPOSED [128+bh][64 d][2048 t].
template <int EPI>
__global__ __launch_bounds__(256, 3)
void gemm_bt(const unsigned short* __restrict__ A, const unsigned short* __restrict__ B,
             const float* __restrict__ bias, void* __restrict__ outv,
             int M, int N, int K) {
  __shared__ __align__(16) unsigned short As[128 * 64];
  __shared__ __align__(16) unsigned short Bs[128 * 64];
  const int tid = threadIdx.x;
  const int l = tid & 63, w = tid >> 6;
  const int wr = w >> 1, wc = w & 1;
  const int tm = blockIdx.x * 128, tn = blockIdx.y * 128;
  const int lr = l >> 3, lc = (l & 7) * 8;

  f32x4 acc[4][4] = {};

  for (int kt = 0; kt < K; kt += 64) {
#pragma unroll
    for (int i = 0; i < 4; ++i) {
      int c = i * 4 + w;
      gload16(A + (size_t)(tm + c * 8 + lr) * K + kt + lc, (char*)As + c * 1024);
    }
#pragma unroll
    for (int i = 0; i < 4; ++i) {
      int c = i * 4 + w;
      gload16(B + (size_t)(tn + c * 8 + lr) * K + kt + lc, (char*)Bs + c * 1024);
    }
    __syncthreads();
#pragma unroll
    for (int ks = 0; ks < 2; ++ks) {
      int ko = ks * 32 + (l >> 4) * 8;
      bf16x8 af[4], bfr[4];
#pragma unroll
      for (int i = 0; i < 4; ++i) {
        af[i]  = *reinterpret_cast<const bf16x8*>(As + (wr * 64 + i * 16 + (l & 15)) * 64 + ko);
        bfr[i] = *reinterpret_cast<const bf16x8*>(Bs + (wc * 64 + i * 16 + (l & 15)) * 64 + ko);
      }
#pragma unroll
      for (int mi = 0; mi < 4; ++mi)
#pragma unroll
        for (int ni = 0; ni < 4; ++ni)
          acc[mi][ni] = mfma16(af[mi], bfr[ni], acc[mi][ni]);
    }
    __syncthreads();
  }

#pragma unroll
  for (int ni = 0; ni < 4; ++ni) {
    int n = tn + wc * 64 + ni * 16 + (l & 15);
    float bv = bias[n];
    if (EPI == 0) {
      float* out = (float*)outv;
#pragma unroll
      for (int mi = 0; mi < 4; ++mi)
#pragma unroll
        for (int r = 0; r < 4; ++r) {
          int m = tm + wr * 64 + mi * 16 + (l >> 4) * 4 + r;
          out[(size_t)m * N + n] = acc[mi][ni][r] + bv;
        }
    } else {
      unsigned short* out = (unsigned short*)outv;
      int s = n >> 10, rem = n & 1023, h = rem >> 6, d = rem & 63;
      if (s == 2) {
        // V transposed: [128 + bh][d][t], 4 consecutive t per lane -> ushort4
#pragma unroll
        for (int mi = 0; mi < 4; ++mi) {
          int m = tm + wr * 64 + mi * 16 + (l >> 4) * 4;
          int bb = m >> 11, t = m & 2047;
          ushort4 pv;
          pv.x = f2bf(acc[mi][ni][0] + bv);
          pv.y = f2bf(acc[mi][ni][1] + bv);
          pv.z = f2bf(acc[mi][ni][2] + bv);
          pv.w = f2bf(acc[mi][ni][3] + bv);
          size_t off = ((size_t)(128 + bb * 16 + h)) * 131072 + (size_t)d * 2048 + t;
          *reinterpret_cast<ushort4*>(out + off) = pv;
        }
      } else {
        const float sc = (s == 0) ? 0.1803368801f : 1.0f;  // fold 0.125*log2(e) into Q
#pragma unroll
        for (int mi = 0; mi < 4; ++mi)
#pragma unroll
          for (int r = 0; r < 4; ++r) {
            int m = tm + wr * 64 + mi * 16 + (l >> 4) * 4 + r;
            int bb = m >> 11, t = m & 2047;
            size_t off = ((((size_t)s * 4 + bb) * 16 + h) * 2048 + t) * 64 + d;
            out[off] = f2bf((acc[mi][ni][r] + bv) * sc);
          }
      }
    }
  }
}

// ---------------- Attention ----------------
// 1024 blocks 1-D, XCD-chunked; qt order 15,0,14,1,... pairs compute-heavy with
// zero-heavy blocks so store traffic is smooth. 4 waves x 32 q-rows. Q in regs.
// Pass 1: BK=128 2-ring; ZERO-FILL of masked cols interleaved per tile (stores
//         overlap pass-1 compute; drained by the per-tile vmcnt(0)).
// Pass 2: K/V^T dbuf, prefetch kt+1; per-wave vmcnt(8) then s_barrier; attnW
//         stores ride one tile (R8/R10-proven).
__global__ __launch_bounds__(256, 3)
void attn_kernel(const unsigned short* __restrict__ qkv, float* __restrict__ attnW,
                 unsigned short* __restrict__ Ob) {
  __shared__ __align__(16) char smem[49152];
  // pass 1: ring {0,1}*16384
  // pass 2: Ks dbuf {0,1}*8192; VsT dbuf 16384+{0,1}*8192; Ps @32768 + w*4096

  const int tid = threadIdx.x, l = tid & 63, w = tid >> 6;
  const int li = l & 15, g = l >> 4;
  const int dd = blockIdx.x;
  const int bh = (dd & 7) + ((dd >> 3) & 7) * 8;
  const int sl6 = dd >> 6;
  const int qt = (sl6 & 1) ? (sl6 >> 1) : (15 - (sl6 >> 1));  // 15,0,14,1,13,2,...
  const int b = bh >> 4, hh = bh & 15;
  const size_t plane = (size_t)2048 * 64;
  const unsigned short* Qg  = qkv + (size_t)bh * plane;
  const unsigned short* Kg  = qkv + ((size_t)64 + bh) * plane;
  const unsigned short* VTg = qkv + ((size_t)128 + bh) * plane;  // [64 d][2048 t]
  const int q0 = qt * 128;
  const int nkt = 2 * qt + 2;

  // ---- Q fragments in registers (wave-private rows; already scaled) ----
  bf16x8 bq[2][2];
#pragma unroll
  for (int qB = 0; qB < 2; ++qB)
#pragma unroll
    for (int ks = 0; ks < 2; ++ks) {
      int cc = ks * 4 + g;
      bq[qB][ks] = *reinterpret_cast<const bf16x8*>(
          Qg + (size_t)(q0 + w * 32 + qB * 16 + li) * 64 + cc * 8);
    }

  auto stageK = [&](int kt64, char* base) {
#pragma unroll
    for (int it = 0; it < 2; ++it) {
      int c = it * 4 + w;
      int X = c * 1024 + l * 16;
      int row = X >> 7, sl = (X >> 4) & 7;
      gload16(Kg + (size_t)(kt64 * 64 + row) * 64 + ((sl ^ (row & 7)) * 8), base + c * 1024);
    }
  };
  auto stageK128 = [&](int kt128, char* base) {
#pragma unroll
    for (int it = 0; it < 4; ++it) {
      int c = it * 4 + w;
      int X = c * 1024 + l * 16;
      int row = X >> 7, sl = (X >> 4) & 7;
      gload16(Kg + (size_t)(kt128 * 128 + row) * 64 + ((sl ^ (row & 7)) * 8), base + c * 1024);
    }
  };
  auto stageVT = [&](int kt64, char* base) {
#pragma unroll
    for (int it = 0; it < 2; ++it) {
      int c = it * 4 + w;
      int X = c * 1024 + l * 16;
      int row = X >> 7, sl = (X >> 4) & 7;   // row = d
      gload16(VTg + (size_t)row * 2048 + kt64 * 64 + ((sl ^ (row & 7)) * 8), base + c * 1024);
    }
  };

  auto computeS = [&](const char* base, f32x4 s[4][2]) {
    const unsigned short* Kp = (const unsigned short*)base;
#pragma unroll
    for (int ks = 0; ks < 2; ++ks) {
      bf16x8 ak[4];
      int cc = ks * 4 + g;
#pragma unroll
      for (int kA = 0; kA < 4; ++kA) {
        int kr = kA * 16 + li;
        ak[kA] = *reinterpret_cast<const bf16x8*>(Kp + kr * 64 + ((cc ^ (kr & 7)) * 8));
      }
#pragma unroll
      for (int kA = 0; kA < 4; ++kA)
#pragma unroll
        for (int qB = 0; qB < 2; ++qB)
          s[kA][qB] = mfma16(ak[kA], bq[qB][ks], s[kA][qB]);
    }
  };

  // zero-fill geometry (masked cols >= col0), sliced across pass-1 tiles
  const int col0 = 128 * (qt + 1);
  const int cpr = (2048 - col0) >> 2;        // f32x4 chunks per row (0 for qt=15)
  const int nkt1 = qt + 1;
  const int rpt = (128 + nkt1 - 1) / nkt1;   // rows per pass-1 tile

  // ---- pass 1: row denominators (m = 0), BK=128, 2-ring + interleaved zero-fill ----
  float lsum[2] = {0.f, 0.f};
  {
    stageK128(0, smem);
    asm volatile("s_waitcnt vmcnt(0)" ::: "memory");
    asm volatile("s_barrier" ::: "memory");
    int cb1 = 0;
    for (int kt = 0; kt < nkt1; ++kt) {
      const int nb1 = cb1 ^ 1;
      if (kt + 1 < nkt1) stageK128(kt + 1, smem + nb1 * 16384);

      // interleaved zero-fill slice (stores overlap this tile's compute)
      if (cpr > 0) {
        int r0 = kt * rpt;
        int r1 = r0 + rpt; if (r1 > 128) r1 = 128;
        f32x4 z = {0.f, 0.f, 0.f, 0.f};
        for (int row = r0; row < r1; ++row) {
          size_t base = ((size_t)bh * 2048 + (q0 + row)) * 2048 + col0;
          for (int c = tid; c < cpr; c += 256)
            __builtin_nontemporal_store(z, reinterpret_cast<f32x4*>(attnW + base + (size_t)c * 4));
        }
      }

      const bool dg = (kt == qt);
#pragma unroll
      for (int half = 0; half < 2; ++half) {
        f32x4 s[4][2] = {};
        computeS(smem + cb1 * 16384 + half * 8192, s);
#pragma unroll
        for (int qB = 0; qB < 2; ++qB) {
          int qg = q0 + w * 32 + qB * 16 + li;
          float a = 0.f;
#pragma unroll
          for (int kA = 0; kA < 4; ++kA)
#pragma unroll
            for (int r = 0; r < 4; ++r) {
              float e = xexp2(s[kA][qB][r]);
              if (dg) { int k = kt * 128 + half * 64 + kA * 16 + g * 4 + r; e = (k <= qg) ? e : 0.f; }
              a += e;
            }
          lsum[qB] += a;
        }
      }
      asm volatile("s_waitcnt vmcnt(0)" ::: "memory");
      asm volatile("s_barrier" ::: "memory");
      cb1 = nb1;
    }
  }

  float linv[2];
#pragma unroll
  for (int qB = 0; qB < 2; ++qB) {
    float v = lsum[qB];
    v += __shfl_xor(v, 16, 64);
    v += __shfl_xor(v, 32, 64);
    linv[qB] = 1.0f / v;
  }

  // ---- pass 2: attnW stores + O = P@V, K/V dbuf + counted vmcnt (R8-proven) ----
  __syncthreads();  // full drain before arena re-carve
  char* KsB = smem;                       // dbuf {0,1}*8192
  char* VsB = smem + 16384;               // dbuf {0,1}*8192
  unsigned short* PsW = (unsigned short*)(smem + 32768 + w * 4096);

  stageK(0, KsB);
  stageVT(0, VsB);
  asm volatile("" ::: "memory");
  asm volatile("s_waitcnt vmcnt(0)" ::: "memory");
  asm volatile("s_barrier" ::: "memory");

  f32x4 o[2][4] = {};
  int cb = 0;

  for (int kt = 0; kt < nkt; ++kt) {
    const int nb = cb ^ 1;
    if (kt + 1 < nkt) { stageK(kt + 1, KsB + nb * 8192); stageVT(kt + 1, VsB + nb * 8192); }
    asm volatile("" ::: "memory");  // pin gload issue before stores

    f32x4 s[4][2] = {};
    computeS(KsB + cb * 8192, s);

    const bool dg = (kt >= 2 * qt);
#pragma unroll
    for (int kA = 0; kA < 4; ++kA)
#pragma unroll
      for (int qB = 0; qB < 2; ++qB) {
        int qg = q0 + w * 32 + qB * 16 + li;
        f32x4 e;
#pragma unroll
        for (int r = 0; r < 4; ++r) {
          float v = xexp2(s[kA][qB][r]) * linv[qB];
          if (dg) { int k = kt * 64 + kA * 16 + g * 4 + r; v = (k <= qg) ? v : 0.f; }
          e[r] = v;
        }
        __builtin_nontemporal_store(e, reinterpret_cast<f32x4*>(
            attnW + ((size_t)bh * 2048 + qg) * 2048 + kt * 64 + kA * 16 + g * 4));
        uint2 pk;
        pk.x = pkbf(e[0], e[1]);
        pk.y = pkbf(e[2], e[3]);
        int qr = qB * 16 + li;
        *reinterpret_cast<uint2*>((char*)PsW + qr * 128 + ((kA * 32 + g * 8) ^ ((qr & 7) << 4))) = pk;
      }

    __builtin_amdgcn_wave_barrier();  // Ps wave-private RAW: pin schedule

    // O^T += V^T x P^T
    const unsigned short* Vp = (const unsigned short*)(VsB + cb * 8192);
#pragma unroll
    for (int ks = 0; ks < 2; ++ks) {
      int cc = ks * 4 + g;
      bf16x8 av[4], bp[2];
#pragma unroll
      for (int df = 0; df < 4; ++df) {
        int dr = df * 16 + li;
        av[df] = *reinterpret_cast<const bf16x8*>(Vp + dr * 64 + ((cc ^ (dr & 7)) * 8));
      }
#pragma unroll
      for (int qB = 0; qB < 2; ++qB) {
        int qr = qB * 16 + li;
        bp[qB] = *reinterpret_cast<const bf16x8*>((const char*)PsW + qr * 128 + ((ks * 64 + g * 16) ^ ((qr & 7) << 4)));
      }
#pragma unroll
      for (int qB = 0; qB < 2; ++qB)
#pragma unroll
        for (int df = 0; df < 4; ++df)
          o[qB][df] = mfma16(av[df], bp[qB], o[qB][df]);
    }

    // retire: prev-tile stores + this tile's 4 gloads; leave this tile's 8 stores in flight.
    // s_barrier AFTER the wait makes kt+1 staging visible to ALL waves (vmcnt is per-wave).
    asm volatile("s_waitcnt vmcnt(8)" ::: "memory");
    asm volatile("s_barrier" ::: "memory");
    cb = nb;
  }

  // ---- O store: lane holds q = qB*16+li, d = df*16 + g*4 + r (O^T layout) ----
#pragma unroll
  for (int qB = 0; qB < 2; ++qB) {
    int qg = q0 + w * 32 + qB * 16 + li;
#pragma unroll
    for (int df = 0; df < 4; ++df) {
      ushort4 ov;
      ov.x = f2bf(o[qB][df][0]);
      ov.y = f2bf(o[qB][df][1]);
      ov.z = f2bf(o[qB][df][2]);
      ov.w = f2bf(o[qB][df][3]);
      *reinterpret_cast<ushort4*>(Ob + ((size_t)b * 2048 + qg) * 1024 + hh * 64 + df * 16 + g * 4) = ov;
    }
  }
}

extern "C" void kernel_launch(void* const* d_in, const int* in_sizes, int n_in,
                              void* d_out, int out_size, void* d_ws, size_t ws_size,
                              hipStream_t stream) {
  const float* x  = (const float*)d_in[0];
  const float* w1 = (const float*)d_in[1];
  const float* b1 = (const float*)d_in[2];
  const float* w2 = (const float*)d_in[3];
  const float* b2 = (const float*)d_in[4];
  float* out = (float*)d_out;
  float* attnW = out + (size_t)8192 * 1024;

  unsigned short* xb   = (unsigned short*)d_ws;
  unsigned short* w1b  = xb + (size_t)8192 * 1024;
  unsigned short* w2b  = w1b + (size_t)3072 * 1024;
  unsigned short* qkvb = w2b + (size_t)1024 * 1024;
  unsigned short* ob   = qkvb + (size_t)3 * 8192 * 1024;

  f2b_kernel<<<1024, 256, 0, stream>>>(x, xb, 8192 * 1024);
  f2b_kernel<<<512, 256, 0, stream>>>(w1, w1b, 3072 * 1024);
  f2b_kernel<<<256, 256, 0, stream>>>(w2, w2b, 1024 * 1024);

  gemm_bt<1><<<dim3(64, 24), 256, 0, stream>>>(xb, w1b, b1, qkvb, 8192, 3072, 1024);

  attn_kernel<<<1024, 256, 0, stream>>>(qkvb, attnW, ob);

  gemm_bt<0><<<dim3(64, 8), 256, 0, stream>>>(ob, w2b, b2, out, 8192, 1024, 1024);
}